// Round 6
// baseline (275.594 us; speedup 1.0000x reference)
//
#include <hip/hip_runtime.h>
#include <stdint.h>

// MHA forward: B=4 T=2048 C=1024 H=16 D=64, causal, fp32 in/out.
// R6: attention reverted to R4 (R5's pairing+launch_bounds regressed: spills +
//     halved residency). GEMM upgraded: 32x32x16 MFMA (fewer, fatter ops),
//     chunk-XOR LDS swizzle (kills 16-way ds_read conflicts), bijective XCD
//     grid swizzle (B-panel L2 locality).

#define B_ 4
#define T_ 2048
#define C_ 1024
#define H_ 16
#define D_ 64
#define M_ (B_ * T_)  // 8192

typedef __attribute__((ext_vector_type(8))) short short8;
typedef __attribute__((ext_vector_type(4))) float f32x4;
typedef __attribute__((ext_vector_type(16))) float f32x16;
typedef __attribute__((ext_vector_type(4))) unsigned short ushort4v;

__device__ __forceinline__ unsigned short f2bf(float f) {
  union { float f; uint32_t u; } v; v.f = f;
  return (unsigned short)((v.u + 0x7fffu + ((v.u >> 16) & 1u)) >> 16);  // RNE
}

__device__ __forceinline__ uint32_t cvt_pk_bf16(float lo, float hi) {
  uint32_t r;
  asm("v_cvt_pk_bf16_f32 %0, %1, %2" : "=v"(r) : "v"(lo), "v"(hi));
  return r;
}

__device__ __forceinline__ void gload_lds16(const unsigned short* g, unsigned short* l) {
  __builtin_amdgcn_global_load_lds(
      (const __attribute__((address_space(1))) void*)g,
      (__attribute__((address_space(3))) void*)l, 16, 0, 0);
}

// ---------------- cast x -> bf16 ----------------
__global__ __launch_bounds__(256) void cast_x_kernel(const float* __restrict__ in,
                                                     unsigned short* __restrict__ out) {
  int i = blockIdx.x * 256 + threadIdx.x;  // exactly M_*C_/4 threads
  f32x4 v = ((const f32x4*)in)[i];
  ushort4v o;
  o[0] = f2bf(v[0]); o[1] = f2bf(v[1]); o[2] = f2bf(v[2]); o[3] = f2bf(v[3]);
  ((ushort4v*)out)[i] = o;
}

// ---------------- W [K][N] f32 -> Wt [N][K] bf16 ----------------
__global__ __launch_bounds__(256) void transpose_w_kernel(const float* __restrict__ W,
                                                          unsigned short* __restrict__ Wt) {
  __shared__ float tile[32][33];
  const int tx = threadIdx.x & 31;
  const int ty = threadIdx.x >> 5;  // 0..7
  const int n0 = blockIdx.x * 32;
  const int k0 = blockIdx.y * 32;
#pragma unroll
  for (int j = 0; j < 4; ++j)
    tile[ty + j * 8][tx] = W[(size_t)(k0 + ty + j * 8) * C_ + n0 + tx];
  __syncthreads();
#pragma unroll
  for (int j = 0; j < 4; ++j)
    Wt[(size_t)(n0 + ty + j * 8) * C_ + k0 + tx] = f2bf(tile[tx][ty + j * 8]);
}

// ---------------- GEMM: C[M][N] = A[M][K] * Bt[N][K]^T ----------------
// 128x128 tile, BK=32, 4 waves (2x2 of 64x64), 32x32x16 MFMA (2x2 frags/wave).
// LDS rows are 4 chunks of 16B; chunk-XOR swizzle c ^= row&3 (linear dest,
// inverse-swizzled global src, swizzled ds_read). Bijective XCD grid swizzle.
// mode 2: o0 = fp32 [M][N], bias b0.
// mode 3: fused qkv; q pre-scaled by 0.125*log2e; v stored transposed.
__global__ __launch_bounds__(256) void gemm_bt_kernel(
    const unsigned short* __restrict__ A, const unsigned short* __restrict__ Bt,
    const float* __restrict__ b0, const float* __restrict__ b1, const float* __restrict__ b2,
    void* __restrict__ o0, void* __restrict__ o1, void* __restrict__ o2,
    int M, int N, int K, int mode, int nblk) {
  __shared__ unsigned short As[128 * 32];
  __shared__ unsigned short Bs[128 * 32];

  const int tid = threadIdx.x;
  const int wv = tid >> 6;
  const int ln = tid & 63;
  const int mtiles = M >> 7;
  // bijective XCD swizzle (nblk % 8 == 0): XCD x owns a contiguous sw-chunk;
  // consecutive sw -> consecutive bm, same bn => shared B-panel in XCD L2.
  const int cpx = nblk >> 3;
  const int sw = (blockIdx.x & 7) * cpx + (blockIdx.x >> 3);
  const int bm = sw % mtiles;
  const int bn = sw / mtiles;
  const int brow = bm << 7;
  const int bcol = bn << 7;

  const int wr = wv >> 1, wc = wv & 1;  // wave -> 64x64 quadrant
  const int lo32 = ln & 31, hi2 = ln >> 5;
  const int srow = ln >> 2;             // staging: 4 lanes/row (4x16B chunks)
  const int sch = ln & 3;               // dest chunk

  f32x16 acc[2][2];
#pragma unroll
  for (int m = 0; m < 2; ++m)
#pragma unroll
    for (int n = 0; n < 2; ++n)
#pragma unroll
      for (int r = 0; r < 16; ++r) acc[m][n][r] = 0.f;

  for (int k0 = 0; k0 < K; k0 += 32) {
    // stage: LDS dest linear; global source chunk = sch ^ (row&3)
#pragma unroll
    for (int j = 0; j < 2; ++j) {
      const int r = j * 64 + wv * 16 + srow;
      const int cs = (sch ^ (r & 3)) << 3;  // element offset of source chunk
      gload_lds16(A + (size_t)(brow + r) * K + k0 + cs, &As[(j * 64 + wv * 16) * 32]);
      gload_lds16(Bt + (size_t)(bcol + r) * K + k0 + cs, &Bs[(j * 64 + wv * 16) * 32]);
    }
    __syncthreads();
    // fragment reads: logical chunk g = ks*2 + hi2, stored at g ^ (row&3)
    short8 af[2][2], bfr[2][2];
#pragma unroll
    for (int mi = 0; mi < 2; ++mi) {
      const int row = wr * 64 + mi * 32 + lo32;
#pragma unroll
      for (int ks = 0; ks < 2; ++ks)
        af[mi][ks] = *(const short8*)(&As[row * 32 + (((ks * 2 + hi2) ^ (row & 3)) << 3)]);
    }
#pragma unroll
    for (int ni = 0; ni < 2; ++ni) {
      const int row = wc * 64 + ni * 32 + lo32;
#pragma unroll
      for (int ks = 0; ks < 2; ++ks)
        bfr[ni][ks] = *(const short8*)(&Bs[row * 32 + (((ks * 2 + hi2) ^ (row & 3)) << 3)]);
    }
#pragma unroll
    for (int mi = 0; mi < 2; ++mi)
#pragma unroll
      for (int ni = 0; ni < 2; ++ni)
#pragma unroll
        for (int ks = 0; ks < 2; ++ks)
          acc[mi][ni] = __builtin_amdgcn_mfma_f32_32x32x16_bf16(af[mi][ks], bfr[ni][ks],
                                                                acc[mi][ni], 0, 0, 0);
    __syncthreads();
  }

  // epilogue: C/D map (32x32): col = lane&31, row = (reg&3) + 8*(reg>>2) + 4*hi2
  const float SCALE_Q = 0.125f * 1.44269504f;
#pragma unroll
  for (int mi = 0; mi < 2; ++mi) {
#pragma unroll
    for (int ni = 0; ni < 2; ++ni) {
      const int rowbase = brow + wr * 64 + mi * 32 + 4 * hi2;
      const int cgc = bcol + wc * 64 + ni * 32 + lo32;
      if (mode == 2) {
        const float bias = b0[cgc];
#pragma unroll
        for (int reg = 0; reg < 16; ++reg) {
          const int row = rowbase + (reg & 3) + 8 * (reg >> 2);
          ((float*)o0)[(size_t)row * N + cgc] = acc[mi][ni][reg] + bias;
        }
      } else {  // mode 3
        const int which = cgc >> 10;  // 0=q 1=k 2=v
        const int cc = cgc & 1023;
        const float bias = ((which == 0) ? b0 : (which == 1) ? b1 : b2)[cc];
        const int h = cc >> 6, d = cc & 63;
#pragma unroll
        for (int reg = 0; reg < 16; ++reg) {
          const int R = rowbase + (reg & 3) + 8 * (reg >> 2);
          const int bb = R >> 11, t = R & (T_ - 1);
          const int bh = bb * H_ + h;
          float val = acc[mi][ni][reg] + bias;
          if (which == 0) val *= SCALE_Q;
          if (which == 2)
            ((unsigned short*)o2)[((size_t)bh * D_ + d) * T_ + t] = f2bf(val);  // v^T
          else
            ((unsigned short*)((which == 0) ? o0 : o1))[((size_t)bh * T_ + t) * D_ + d] = f2bf(val);
        }
      }
    }
  }
}

// ---------------- flash attention (swapped-operand 32x32) — R4 version ------
// block = (bh, 128 q-rows); 4 warps x 32 rows. KVBLK=64.
// K: double-buffered XOR-swizzled LDS. V^T: direct global/L2 fragment loads.
// Softmax per lane pair {l, l^32}; P packed via v_cvt_pk_bf16_f32, woven by
// shfl_xor(32) into PV B-fragments. Defer-max (THR=8) skips most rescales.
__global__ __launch_bounds__(256) void attn_kernel(
    const unsigned short* __restrict__ Q, const unsigned short* __restrict__ Kb,
    const unsigned short* __restrict__ Vt, unsigned short* __restrict__ Y) {
  __shared__ unsigned short Ks[2][64 * 64];   // [s][chunk-swizzled d]

  // bijective XCD swizzle: blk -> (xcd = blk&7) gets bh in [8*xcd, 8*xcd+8),
  // heavy q-tiles (qt=15) first within each XCD group.
  const int blk = blockIdx.x;
  const int xcd = blk & 7;
  const int j = blk >> 3;              // 0..127
  const int bh = xcd * 8 + (j & 7);    // 0..63
  const int qt = 15 - (j >> 3);        // 15..0
  const int wv = threadIdx.x >> 6;
  const int ln = threadIdx.x & 63;
  const int q31 = ln & 31;
  const int hi = ln >> 5;
  const int r0 = qt * 128 + wv * 32;

  const unsigned short* kp = Kb + (size_t)bh * T_ * D_;
  const unsigned short* vp = Vt + (size_t)bh * D_ * T_;

  // staging lane geometry: one gload_lds = 64 lanes x 16B = 8 rows x 8 chunks
  const int sr = ln >> 3;
  const int scc = ln & 7;
  const int krow = wv * 16;  // this wave stages K rows [krow, krow+16)

  // Q fragments (global, once): qf[kd] = Q[q=r0+q31][kd*16 + hi*8 .. +8)
  const unsigned short* qp = Q + ((size_t)bh * T_ + r0) * D_;
  short8 qf[4];
#pragma unroll
  for (int kd = 0; kd < 4; ++kd)
    qf[kd] = *(const short8*)(qp + (size_t)q31 * D_ + kd * 16 + hi * 8);

  f32x16 o0, o1;
#pragma unroll
  for (int r = 0; r < 16; ++r) { o0[r] = 0.f; o1[r] = 0.f; }
  float mr = -1e38f, lr = 0.f;

  auto stage = [&](int b, int s0) {
#pragma unroll
    for (int jj = 0; jj < 2; ++jj) {
      const int r = krow + jj * 8 + sr;
      const int cs = (scc ^ (r & 7)) << 3;  // inverse-swizzled source chunk
      gload_lds16(kp + (size_t)(s0 + r) * D_ + cs, &Ks[b][(krow + jj * 8) * 64]);
    }
  };

  const int nt = 2 * qt + 2;
  const int it_last = (r0 + 31) >> 6;  // last active tile for this warp
  stage(0, 0);
  __syncthreads();
  int buf = 0;

  for (int it = 0; it < nt; ++it) {
    const int s0 = it << 6;
    if (it + 1 < nt) stage(buf ^ 1, s0 + 64);

    if (it <= it_last) {
      // ---- V^T fragments from global/L2 (issued early for latency hiding)
      short8 vfr0[4], vfr1[4];
      const unsigned short* vb0 = vp + (size_t)q31 * T_ + s0 + hi * 8;
#pragma unroll
      for (int ks = 0; ks < 4; ++ks) {
        vfr0[ks] = *(const short8*)(vb0 + ks * 16);
        vfr1[ks] = *(const short8*)(vb0 + (size_t)32 * T_ + ks * 16);
      }

      // ---- QK^T (swapped): S[s][q], s = crow(r,hi)+32*tau, q = lane&31 ----
      f32x16 sa0, sa1;
#pragma unroll
      for (int r = 0; r < 16; ++r) { sa0[r] = 0.f; sa1[r] = 0.f; }
#pragma unroll
      for (int kd = 0; kd < 4; ++kd) {
        const short8 kf0 =
            *(const short8*)(&Ks[buf][q31 * 64 + (((2 * kd + hi) ^ (q31 & 7)) << 3)]);
        sa0 = __builtin_amdgcn_mfma_f32_32x32x16_bf16(kf0, qf[kd], sa0, 0, 0, 0);
      }
#pragma unroll
      for (int kd = 0; kd < 4; ++kd) {
        const int row = 32 + q31;
        const short8 kf1 =
            *(const short8*)(&Ks[buf][row * 64 + (((2 * kd + hi) ^ (row & 7)) << 3)]);
        sa1 = __builtin_amdgcn_mfma_f32_32x32x16_bf16(kf1, qf[kd], sa1, 0, 0, 0);
      }

      // ---- causal mask: only the last active tile crosses the diagonal ----
      if (it == it_last) {
        const int qg = r0 + q31;
#pragma unroll
        for (int r = 0; r < 16; ++r) {
          const int sl = (r & 3) + ((r >> 2) << 3) + hi * 4;  // crow(r,hi)
          if (s0 + sl > qg) sa0[r] = -1e38f;
          if (s0 + 32 + sl > qg) sa1[r] = -1e38f;
        }
      }

      // ---- online softmax (exp2 domain; Q pre-scaled). defer-max THR=8 ----
      float pm = -1e38f;
#pragma unroll
      for (int r = 0; r < 16; ++r) pm = fmaxf(pm, fmaxf(sa0[r], sa1[r]));
      pm = fmaxf(pm, __shfl_xor(pm, 32));
      if (__any(pm > mr + 8.0f)) {
        const float mn = fmaxf(mr, pm);
        const float alpha = exp2f(mr - mn);
        mr = mn;
        lr *= alpha;
#pragma unroll
        for (int r = 0; r < 16; ++r) { o0[r] *= alpha; o1[r] *= alpha; }
      }
      float rsa = 0.f, rsb = 0.f;
#pragma unroll
      for (int r = 0; r < 16; ++r) {
        const float p0 = exp2f(sa0[r] - mr);
        const float p1 = exp2f(sa1[r] - mr);
        sa0[r] = p0; sa1[r] = p1;
        rsa += p0; rsb += p1;
      }
      float rs = rsa + rsb;
      rs += __shfl_xor(rs, 32);
      lr += rs;

      // ---- pack P to bf16 words (v_cvt_pk_bf16_f32) ----
      uint32_t pk[16];
#pragma unroll
      for (int u = 0; u < 4; ++u)
#pragma unroll
        for (int vp2 = 0; vp2 < 2; ++vp2) {
          pk[2 * u + vp2]     = cvt_pk_bf16(sa0[4 * u + 2 * vp2], sa0[4 * u + 2 * vp2 + 1]);
          pk[8 + 2 * u + vp2] = cvt_pk_bf16(sa1[4 * u + 2 * vp2], sa1[4 * u + 2 * vp2 + 1]);
        }

      // ---- weave (shfl_xor 32) + PV: pf[j] = P[q][16ks + 8hi + j] ----
#pragma unroll
      for (int ks = 0; ks < 4; ++ks) {
        const uint32_t x0 = hi ? pk[4 * ks + 2] : pk[4 * ks + 0];
        const uint32_t x1 = hi ? pk[4 * ks + 3] : pk[4 * ks + 1];
        const uint32_t y0 = hi ? pk[4 * ks + 0] : pk[4 * ks + 2];
        const uint32_t y1 = hi ? pk[4 * ks + 1] : pk[4 * ks + 3];
        const uint32_t g0 = (uint32_t)__shfl_xor((int)y0, 32);
        const uint32_t g1 = (uint32_t)__shfl_xor((int)y1, 32);
        union { uint32_t w[4]; short8 v; } pf;
        pf.w[0] = hi ? g0 : x0;
        pf.w[1] = hi ? g1 : x1;
        pf.w[2] = hi ? x0 : g0;
        pf.w[3] = hi ? x1 : g1;
        o0 = __builtin_amdgcn_mfma_f32_32x32x16_bf16(vfr0[ks], pf.v, o0, 0, 0, 0);
        o1 = __builtin_amdgcn_mfma_f32_32x32x16_bf16(vfr1[ks], pf.v, o1, 0, 0, 0);
      }
    }
    __syncthreads();
    buf ^= 1;
  }

  // ---- epilogue: lane owns q = r0+q31; d = crow(r,hi) + 32*{0,1} ----
  const int b = bh >> 4, h = bh & 15;
  const float inv = 1.f / lr;
  const int t = r0 + q31;
  unsigned short* yrow = Y + ((size_t)(b * T_ + t)) * C_ + h * 64;
#pragma unroll
  for (int u = 0; u < 4; ++u) {
    union { uint32_t w[2]; ushort4v v; } w0, w1;
    w0.w[0] = cvt_pk_bf16(o0[4 * u + 0] * inv, o0[4 * u + 1] * inv);
    w0.w[1] = cvt_pk_bf16(o0[4 * u + 2] * inv, o0[4 * u + 3] * inv);
    w1.w[0] = cvt_pk_bf16(o1[4 * u + 0] * inv, o1[4 * u + 1] * inv);
    w1.w[1] = cvt_pk_bf16(o1[4 * u + 2] * inv, o1[4 * u + 3] * inv);
    *(ushort4v*)(yrow + u * 8 + hi * 4) = w0.v;
    *(ushort4v*)(yrow + 32 + u * 8 + hi * 4) = w1.v;
  }
}

extern "C" void kernel_launch(void* const* d_in, const int* in_sizes, int n_in,
                              void* d_out, int out_size, void* d_ws, size_t ws_size,
                              hipStream_t stream) {
  const float* x  = (const float*)d_in[0];
  // d_in[1] = causal mask (tril) — implemented analytically, unused
  const float* Wq = (const float*)d_in[2];
  const float* bq = (const float*)d_in[3];
  const float* Wk = (const float*)d_in[4];
  const float* bk = (const float*)d_in[5];
  const float* Wv = (const float*)d_in[6];
  const float* bv = (const float*)d_in[7];
  const float* Wp = (const float*)d_in[8];
  const float* bp = (const float*)d_in[9];
  float* out = (float*)d_out;

  // workspace layout (bytes); total 76 MiB
  uint8_t* ws = (uint8_t*)d_ws;
  if (ws_size < (76u << 20)) return;  // insufficient scratch -> clean validation failure
  unsigned short* xb  = (unsigned short*)(ws);                 // 16 MiB; reused as Y after attention
  unsigned short* wqT = (unsigned short*)(ws + (16u << 20));   // 2 MiB each; wq/wk/wv contiguous => [3072][1024]
  unsigned short* wkT = (unsigned short*)(ws + (18u << 20));
  unsigned short* wvT = (unsigned short*)(ws + (20u << 20));
  unsigned short* wpT = (unsigned short*)(ws + (22u << 20));
  unsigned short* qb  = (unsigned short*)(ws + (24u << 20));   // 16 MiB [BH][T][D] (pre-scaled)
  unsigned short* kb  = (unsigned short*)(ws + (40u << 20));   // 16 MiB [BH][T][D]
  unsigned short* vtb = (unsigned short*)(ws + (56u << 20));   // 16 MiB [BH][D][T]

  cast_x_kernel<<<(M_ * C_ / 4) / 256, 256, 0, stream>>>(x, xb);
  dim3 tg(32, 32);
  transpose_w_kernel<<<tg, 256, 0, stream>>>(Wq, wqT);
  transpose_w_kernel<<<tg, 256, 0, stream>>>(Wk, wkT);
  transpose_w_kernel<<<tg, 256, 0, stream>>>(Wv, wvT);
  transpose_w_kernel<<<tg, 256, 0, stream>>>(Wp, wpT);

  // fused QKV: M=8192, N=3072, K=1024 -> 64*24 = 1536 blocks (1536%8==0)
  {
    const int nblk = (M_ / 128) * (3 * C_ / 128);
    gemm_bt_kernel<<<nblk, 256, 0, stream>>>(
        xb, wqT, bq, bk, bv, qb, kb, vtb, M_, 3 * C_, C_, 3, nblk);
  }

  attn_kernel<<<B_ * H_ * (T_ / 128), 256, 0, stream>>>(qb, kb, vtb, xb);

  // output projection: M=8192, N=1024, K=1024 -> 64*8 = 512 blocks
  {
    const int nblk = (M_ / 128) * (C_ / 128);
    gemm_bt_kernel<<<nblk, 256, 0, stream>>>(
        xb, wpT, bp, nullptr, nullptr, out, nullptr, nullptr, M_, C_, C_, 2, nblk);
  }
}